// Round 4
// baseline (238.403 us; speedup 1.0000x reference)
//
#include <hip/hip_runtime.h>
#include <hip/hip_cooperative_groups.h>
#include <math.h>

namespace cg = cooperative_groups;

#define EPSF 1e-8f
#define Tn 512
#define Dn 64
#define NELEM 65536

__device__ __forceinline__ float sigmoidf_(float x){ return 1.0f/(1.0f+__expf(-x)); }
__device__ __forceinline__ float softplusf_(float x){ return fmaxf(x,0.0f) + log1pf(__expf(-fabsf(x))); }

__device__ __forceinline__ float wrs(float v){
  #pragma unroll
  for (int off=1; off<64; off<<=1) v += __shfl_xor(v, off, 64);
  return v;
}
__device__ __forceinline__ float wrm(float v){
  #pragma unroll
  for (int off=1; off<64; off<<=1) v = fmaxf(v, __shfl_xor(v, off, 64));
  return v;
}

// ======================= fused cooperative path (NI=4) =======================

// pnorm, one wave per row (i = wave index 0..3). Writes:
//  - s4[k*4+i] (LDS operand for next dot)
//  - sT_out k4-major: float4 [(b*16+k4)*512 + r] = {sq[4k4..4k4+3]} via shuffle
__device__ __forceinline__ void pnorm4(float xg, int b, int r, int i, int lane,
                                       float* __restrict__ sT_out, float* __restrict__ s4){
  float s = softplusf_(xg);
  float sum = wrs(s);
  float p = fmaxf(s/(sum+EPSF), EPSF);
  float s2 = wrs(p);
  float sq = sqrtf(p/(s2+EPSF));
  s4[lane*4 + i] = sq;
  int base = (lane*4)&63;
  float4 v;
  v.x = __shfl(sq, base,   64);
  v.y = __shfl(sq, base+1, 64);
  v.z = __shfl(sq, base+2, 64);
  v.w = __shfl(sq, base+3, 64);
  if (lane < 16)
    ((float4*)sT_out)[((size_t)b*16 + lane)*512 + r] = v;
}

// gate dot NI=4: 8 threads per output d, each dots 16 of 128, for 4 rows
__device__ __forceinline__ void gate_dot4(float (*comb)[128], float (*gred)[4],
                                          const float* __restrict__ Wfb, int tid, int lane){
  int dd = tid >> 3, k8 = tid & 7;
  const float4* wp = (const float4*)(Wfb + (size_t)dd*128 + k8*16);
  float4 w0 = wp[0], w1 = wp[1], w2 = wp[2], w3 = wp[3];
  float ga[4];
  #pragma unroll
  for (int i=0;i<4;i++){
    const float4* c4 = (const float4*)&comb[i][k8*16];
    float4 c0=c4[0], c1=c4[1], c2=c4[2], c3=c4[3];
    ga[i] = w0.x*c0.x + w0.y*c0.y + w0.z*c0.z + w0.w*c0.w
          + w1.x*c1.x + w1.y*c1.y + w1.z*c1.z + w1.w*c1.w
          + w2.x*c2.x + w2.y*c2.y + w2.z*c2.z + w2.w*c2.w
          + w3.x*c3.x + w3.y*c3.y + w3.z*c3.z + w3.w*c3.w;
  }
  #pragma unroll
  for (int off=1; off<8; off<<=1){
    #pragma unroll
    for (int i=0;i<4;i++) ga[i] += __shfl_xor(ga[i], off, 64);
  }
  if ((lane&7)==0){
    #pragma unroll
    for (int i=0;i<4;i++) gred[dd][i] = ga[i];
  }
}

// 256 blocks x 512 threads = 1 block/CU (guaranteed residency margin).
// Block owns rows {4bid..4bid+3}; 9 grid.sync()s replace the 10-dispatch chain.
__global__ __launch_bounds__(512, 2) void k_fused(
    const float* __restrict__ basin_seq, const float* __restrict__ basin_coords,
    const float* __restrict__ W_temp, const float* __restrict__ b_temp,
    const float* __restrict__ res_scale,
    const float* __restrict__ W_fb, const float* __restrict__ b_fb,
    const float* __restrict__ Wc1, const float* __restrict__ bc1,
    const float* __restrict__ Wc2, const float* __restrict__ bc2,
    const float* __restrict__ Wu, const float* __restrict__ bu,
    const float* __restrict__ rsg, float* __restrict__ out, float* __restrict__ ws){

  __shared__ __align__(16) float pvp[128*64];  // [(jg*4+i)][d]  32 KB
  __shared__ __align__(16) float P[512*4];     // [j][i]          8 KB
  __shared__ __align__(16) float s4[64*4];     // [k][i]          1 KB
  __shared__ float redw[2][8][4];
  __shared__ __align__(16) float comb[4][128];
  __shared__ __align__(16) float gred[64][4];
  __shared__ float temps_l[8];                 // [0..3] pass0, [4..7] pass1
  __shared__ float rs_l[4];
  __shared__ float pooled_l[128];
  __shared__ float h1l[64];
  __shared__ float hbl[128];
  __shared__ float combb[128];
  __shared__ float nb_l[64];

  cg::grid_group grid = cg::this_grid();

  int tid = threadIdx.x, wav = tid>>6, lane = tid&63;
  int bid = blockIdx.x;
  int row0 = bid*4;
  int b = row0>>9;
  int rb = row0&511;
  int i_ = tid>>6, d_ = lane;   // (row, dim) mapping for tid<256

  float* sTA = ws;
  float* sTB = ws +  (size_t)NELEM;
  float* st0 = ws + 2*(size_t)NELEM;
  float* st1 = ws + 3*(size_t)NELEM;
  float* st2g= ws + 4*(size_t)NELEM;
  float* xAg = ws + 5*(size_t)NELEM;
  float* xBg = ws + 6*(size_t)NELEM;
  float* xCg = ws + 7*(size_t)NELEM;
  float* xDg = ws + 8*(size_t)NELEM;
  float* pooled_g = ws + 9*(size_t)NELEM;      // 128 floats

  float bs_r=0.f, xi_pre=0.f, st0_r=0.f, st1_r=0.f, st2_r=0.f, st3_r=0.f;

  auto ATTN = [&](const float* __restrict__ xin, const float* __restrict__ sTin,
                  int tidx, float rs) -> float {
    float invT = 1.0f/fmaxf(temps_l[tidx], 1e-6f);
    // dot: thread j = tid computes inner(i,j) for all 4 rows
    float a0=0.f, a1=0.f, a2=0.f, a3=0.f;
    {
      const float4* sT4 = (const float4*)sTin + (size_t)b*16*512;
      const float4* s4p = (const float4*)s4;
      #pragma unroll
      for (int c=0;c<16;++c){
        float4 kv = sT4[(size_t)c*512 + tid];     // coalesced across lanes
        float4 sa = s4p[4*c],   sb2 = s4p[4*c+1]; // LDS broadcast
        float4 sc = s4p[4*c+2], sd  = s4p[4*c+3];
        a0=fmaf(kv.x,sa.x,a0);  a1=fmaf(kv.x,sa.y,a1);
        a2=fmaf(kv.x,sa.z,a2);  a3=fmaf(kv.x,sa.w,a3);
        a0=fmaf(kv.y,sb2.x,a0); a1=fmaf(kv.y,sb2.y,a1);
        a2=fmaf(kv.y,sb2.z,a2); a3=fmaf(kv.y,sb2.w,a3);
        a0=fmaf(kv.z,sc.x,a0);  a1=fmaf(kv.z,sc.y,a1);
        a2=fmaf(kv.z,sc.z,a2);  a3=fmaf(kv.z,sc.w,a3);
        a0=fmaf(kv.w,sd.x,a0);  a1=fmaf(kv.w,sd.y,a1);
        a2=fmaf(kv.w,sd.z,a2);  a3=fmaf(kv.w,sd.w,a3);
      }
    }
    // logits + softmax
    float lg[4];
    {
      float aa[4] = {a0,a1,a2,a3};
      #pragma unroll
      for (int i=0;i<4;i++){
        float cc = fminf(fmaxf(aa[i],-1.0f+1e-6f),1.0f-1e-6f);
        lg[i] = -2.0f*acosf(cc)*invT;
        float m = wrm(lg[i]);
        if (lane==0) redw[0][wav][i] = m;
      }
    }
    __syncthreads();
    {
      float e[4];
      #pragma unroll
      for (int i=0;i<4;i++){
        float mv = redw[0][0][i];
        #pragma unroll
        for (int w=1;w<8;w++) mv = fmaxf(mv, redw[0][w][i]);
        e[i] = __expf(lg[i]-mv);
      }
      *(float4*)&P[tid*4] = make_float4(e[0],e[1],e[2],e[3]);
      #pragma unroll
      for (int i=0;i<4;i++){
        float q = wrs(e[i]);
        if (lane==0) redw[1][wav][i] = q;
      }
    }
    __syncthreads();
    // PV: thread (jg,dq); 16 j's, float4 along d
    {
      int jg = tid>>4, dq = tid&15;
      const float4* x4p = (const float4*)(xin + (size_t)b*Tn*Dn);
      float4 o0={0,0,0,0}, o1={0,0,0,0}, o2={0,0,0,0}, o3={0,0,0,0};
      int jb = jg*16;
      #pragma unroll
      for (int jj=0; jj<16; ++jj){
        int j = jb + jj;
        float4 xv = x4p[(size_t)j*16 + dq];
        float4 pw = *(const float4*)&P[j*4];
        o0.x=fmaf(pw.x,xv.x,o0.x); o0.y=fmaf(pw.x,xv.y,o0.y);
        o0.z=fmaf(pw.x,xv.z,o0.z); o0.w=fmaf(pw.x,xv.w,o0.w);
        o1.x=fmaf(pw.y,xv.x,o1.x); o1.y=fmaf(pw.y,xv.y,o1.y);
        o1.z=fmaf(pw.y,xv.z,o1.z); o1.w=fmaf(pw.y,xv.w,o1.w);
        o2.x=fmaf(pw.z,xv.x,o2.x); o2.y=fmaf(pw.z,xv.y,o2.y);
        o2.z=fmaf(pw.z,xv.z,o2.z); o2.w=fmaf(pw.z,xv.w,o2.w);
        o3.x=fmaf(pw.w,xv.x,o3.x); o3.y=fmaf(pw.w,xv.y,o3.y);
        o3.z=fmaf(pw.w,xv.z,o3.z); o3.w=fmaf(pw.w,xv.w,o3.w);
      }
      *(float4*)&pvp[(jg*4+0)*64 + dq*4] = o0;
      *(float4*)&pvp[(jg*4+1)*64 + dq*4] = o1;
      *(float4*)&pvp[(jg*4+2)*64 + dq*4] = o2;
      *(float4*)&pvp[(jg*4+3)*64 + dq*4] = o3;
    }
    __syncthreads();
    float o = 0.f;
    if (tid < 256){
      float ss = 0.f;
      #pragma unroll
      for (int jg=0; jg<32; ++jg) ss += pvp[(jg*4+i_)*64+d_];
      float sv = 0.f;
      #pragma unroll
      for (int w=0;w<8;w++) sv += redw[1][w][i_];
      o = xi_pre + rs*(ss/sv - xi_pre);
    }
    return o;
  };

  auto GATE_WRITE = [&](float xv, float pv, const float* __restrict__ Wl,
                        const float* __restrict__ bl,
                        float* __restrict__ xoutp, float* __restrict__ sToutp) -> float {
    if (tid < 256){ comb[i_][d_]=xv; comb[i_][64+d_]=pv; }
    __syncthreads();
    gate_dot4(comb, gred, Wl, tid, lane);
    __syncthreads();
    float xg = 0.f;
    if (tid < 256){
      float g = sigmoidf_(gred[d_][i_] + bl[d_]);
      xg = xv*g + pv*(1.0f-g);
      xoutp[(size_t)(row0+i_)*Dn + d_] = xg;
      pnorm4(xg, b, rb+i_, i_, lane, sToutp, s4);
    }
    return xg;
  };

  // ---- Stage A: prologue
  if (tid < 4) rs_l[tid] = res_scale[tid];
  if (tid < 64){
    float cbv = basin_coords[tid];
    #pragma unroll
    for (int l=0;l<4;l++){
      float v = wrs(W_temp[l*Dn + tid]*cbv);
      if (tid==0) temps_l[l] = sigmoidf_(v + b_temp[l]) + 0.5f;
    }
  }
  if (bid==0 && tid<128) pooled_g[tid] = 0.f;
  if (tid < 256){
    bs_r = basin_seq[(size_t)(row0+i_)*Dn + d_];
    xi_pre = bs_r;
    pnorm4(bs_r, b, rb+i_, i_, lane, sTA, s4);
  }
  grid.sync();

  // ---- Pass 0
  { // L0
    float o = ATTN(basin_seq, sTA, 0, rs_l[0]);
    if (tid < 256){
      st0_r = o; xi_pre = o;
      st0[(size_t)(row0+i_)*Dn + d_] = o;
      pnorm4(o, b, rb+i_, i_, lane, sTB, s4);
    }
    grid.sync();
  }
  { // L1
    float o = ATTN(st0, sTB, 1, rs_l[1]);
    if (tid < 256){
      st1_r = o; xi_pre = o;
      st1[(size_t)(row0+i_)*Dn + d_] = o;
      pnorm4(o, b, rb+i_, i_, lane, sTA, s4);
    }
    grid.sync();
  }
  { // L2
    float o = ATTN(st1, sTA, 2, rs_l[2]);
    if (tid < 256){
      st2_r = o; xi_pre = o;
      st2g[(size_t)(row0+i_)*Dn + d_] = o;
      pnorm4(o, b, rb+i_, i_, lane, sTB, s4);
    }
    grid.sync();
  }
  { // L3: keep in regs; pooled via per-block pre-reduction + atomics
    float o = ATTN(st2g, sTB, 3, rs_l[3]);
    if (tid < 256){ st3_r = o; xi_pre = o; comb[i_][d_] = o; }
    __syncthreads();
    if (tid < 64)
      atomicAdd(&pooled_g[b*Dn + d_],
                (comb[0][d_]+comb[1][d_]+comb[2][d_]+comb[3][d_]) * (1.0f/Tn));
    grid.sync();
  }

  // ---- Stage F: basin update (redundant per block) + P1L0 gate
  {
    if (tid < 128) pooled_l[tid] = pooled_g[tid];
    __syncthreads();
    if (tid < 64){
      int bb = tid>>5, h = tid&31;
      float acc=0.f;
      #pragma unroll 8
      for (int d2=0; d2<64; d2++) acc += pooled_l[bb*64+d2]*Wc1[h*64+d2];
      h1l[tid] = tanhf(acc + bc1[h]);
    }
    __syncthreads();
    if (tid < 128){
      int bb = tid>>6, d = tid&63;
      float acc=0.f;
      #pragma unroll 8
      for (int h2=0; h2<32; h2++) acc += h1l[bb*32+h2]*Wc2[d*32+h2];
      hbl[tid] = tanhf(acc + bc2[d]);
    }
    __syncthreads();
    if (tid < 64){
      combb[tid] = basin_coords[tid];
      combb[64+tid] = 0.5f*(hbl[tid] + hbl[64+tid]);
    }
    __syncthreads();
    if (tid < 64){
      float acc=0.f;
      #pragma unroll 8
      for (int k=0;k<128;k++) acc += Wu[tid*128+k]*combb[k];
      float g = sigmoidf_(acc + bu[tid]);
      nb_l[tid] = combb[tid]*(1.0f-g) + combb[64+tid]*g;
    }
    __syncthreads();
    if (tid < 64){
      float nb = nb_l[tid];
      #pragma unroll
      for (int l=0;l<4;l++){
        float v = wrs(W_temp[l*Dn + tid]*nb);
        if (tid==0) temps_l[4+l] = sigmoidf_(v + b_temp[l]) + 0.5f;
      }
    }
    float xg = GATE_WRITE(st3_r, st0_r, W_fb, b_fb, xAg, sTA);
    if (tid < 256) xi_pre = xg;
    grid.sync();
  }

  // ---- Pass 1
  { // P1 L0 + gate l=1 (prev=st1)
    float o = ATTN(xAg, sTA, 4, rs_l[0]);
    float xg = GATE_WRITE(o, st1_r, W_fb + (size_t)1*Dn*2*Dn, b_fb + 1*Dn, xBg, sTB);
    if (tid < 256) xi_pre = xg;
    grid.sync();
  }
  { // P1 L1 + gate l=2 (prev=st2)
    float o = ATTN(xBg, sTB, 5, rs_l[1]);
    float xg = GATE_WRITE(o, st2_r, W_fb + (size_t)2*Dn*2*Dn, b_fb + 2*Dn, xCg, sTA);
    if (tid < 256) xi_pre = xg;
    grid.sync();
  }
  { // P1 L2 + gate l=3 (prev=st3)
    float o = ATTN(xCg, sTA, 6, rs_l[2]);
    float xg = GATE_WRITE(o, st3_r, W_fb + (size_t)3*Dn*2*Dn, b_fb + 3*Dn, xDg, sTB);
    if (tid < 256) xi_pre = xg;
    grid.sync();
  }
  { // P1 L3 + final residual
    float o = ATTN(xDg, sTB, 7, rs_l[3]);
    if (tid < 256){
      float c = 0.01f * rsg[0];
      out[(size_t)(row0+i_)*Dn + d_] = o + c*(o - bs_r);
    }
  }
}

// ======================= fallback path (round-2, known-PASS) =======================

__device__ __forceinline__ void pnorm_w(float xg, int row, int d, float* __restrict__ sr_out){
  float s = softplusf_(xg);
  float sum = wrs(s);
  float p = fmaxf(s/(sum+EPSF), EPSF);
  float s2 = wrs(p);
  sr_out[(size_t)row*Dn + d] = sqrtf(p/(s2+EPSF));
}

__global__ __launch_bounds__(256) void k_prologue(
    const float* __restrict__ basin_seq, float* __restrict__ sA,
    const float* __restrict__ W_temp, const float* __restrict__ b_temp,
    const float* __restrict__ cb0, float* __restrict__ temps){
  int tid = threadIdx.x, wid = tid>>6, lane = tid&63;
  if (blockIdx.x < 256){
    int row = blockIdx.x*4 + wid;
    pnorm_w(basin_seq[(size_t)row*Dn+lane], row, lane, sA);
  } else if (tid < 64){
    float cbv = cb0[tid];
    #pragma unroll
    for (int l=0;l<4;l++){
      float v = wrs(W_temp[l*Dn + tid]*cbv);
      if (tid==0) temps[l] = sigmoidf_(v + b_temp[l]) + 0.5f;
    }
  }
}

__device__ __forceinline__ void gate_dot2(float (*comb)[128], float* gred,
                                          const float* __restrict__ Wfb, int tid, int lane){
  int dd = tid >> 3, k8 = tid & 7;
  const float4* wp = (const float4*)(Wfb + (size_t)dd*128 + k8*16);
  float4 w0 = wp[0], w1 = wp[1], w2 = wp[2], w3 = wp[3];
  float ga[2];
  #pragma unroll
  for (int i=0;i<2;i++){
    float4 c0 = *(const float4*)&comb[i][k8*16];
    float4 c1 = *(const float4*)&comb[i][k8*16+4];
    float4 c2 = *(const float4*)&comb[i][k8*16+8];
    float4 c3 = *(const float4*)&comb[i][k8*16+12];
    ga[i] = w0.x*c0.x + w0.y*c0.y + w0.z*c0.z + w0.w*c0.w
          + w1.x*c1.x + w1.y*c1.y + w1.z*c1.z + w1.w*c1.w
          + w2.x*c2.x + w2.y*c2.y + w2.z*c2.z + w2.w*c2.w
          + w3.x*c3.x + w3.y*c3.y + w3.z*c3.z + w3.w*c3.w;
  }
  #pragma unroll
  for (int off=1; off<8; off<<=1){
    ga[0] += __shfl_xor(ga[0],off,64); ga[1] += __shfl_xor(ga[1],off,64);
  }
  if ((lane&7)==0){ gred[dd*3+0]=ga[0]; gred[dd*3+1]=ga[1]; }
}

template<int MODE>
__global__ __launch_bounds__(512) void k_attn(
    const float* __restrict__ xin, const float* __restrict__ sr,
    const float* __restrict__ temps, const float* __restrict__ res_scale, int l,
    float* __restrict__ xout, float* __restrict__ sr_out,
    const float* __restrict__ Wfb, const float* __restrict__ bfb,
    const float* __restrict__ prev,
    const float* __restrict__ basin_seq, const float* __restrict__ rsg){
  __shared__ __align__(16) float pvp[64*64];
  __shared__ __align__(8)  float P[512*2];
  __shared__ __align__(16) float s01[64*2];
  __shared__ float redw[2][8][2];
  __shared__ __align__(16) float comb[2][128];
  __shared__ float gred[64*3];

  int tid = threadIdx.x, wav = tid>>6, lane = tid&63;
  int row0 = blockIdx.x*2, b = row0>>9;
  int i_ = tid>>6, d_ = lane;

  float xi_pre = 0.f, prev_pre = 0.f;
  if (tid < 128){
    s01[d_*2 + i_] = sr[(size_t)(row0+i_)*Dn + d_];
    xi_pre = xin[(size_t)(row0+i_)*Dn + d_];
    if constexpr (MODE == 2) prev_pre = prev[(size_t)(row0+i_)*Dn + d_];
  }
  __syncthreads();

  float invT = 1.0f/fmaxf(temps[l], 1e-6f);

  float a0=0.f, a1=0.f, b0=0.f, b1=0.f;
  {
    const float4* rj4 = (const float4*)(sr + (size_t)b*Tn*Dn + (size_t)tid*Dn);
    const float4* sp  = (const float4*)s01;
    #pragma unroll 8
    for (int c=0;c<16;++c){
      float4 x4 = rj4[c];
      float4 sa = sp[2*c], sb = sp[2*c+1];
      a0 = fmaf(x4.x, sa.x, a0); a1 = fmaf(x4.x, sa.y, a1);
      b0 = fmaf(x4.y, sa.z, b0); b1 = fmaf(x4.y, sa.w, b1);
      a0 = fmaf(x4.z, sb.x, a0); a1 = fmaf(x4.z, sb.y, a1);
      b0 = fmaf(x4.w, sb.z, b0); b1 = fmaf(x4.w, sb.w, b1);
    }
    a0 += b0; a1 += b1;
  }
  {
    float c0 = fminf(fmaxf(a0,-1.0f+1e-6f),1.0f-1e-6f);
    float c1 = fminf(fmaxf(a1,-1.0f+1e-6f),1.0f-1e-6f);
    float l0 = -2.0f*acosf(c0)*invT;
    float l1 = -2.0f*acosf(c1)*invT;
    float m0=wrm(l0), m1=wrm(l1);
    if (lane==0){ redw[0][wav][0]=m0; redw[0][wav][1]=m1; }
    __syncthreads();
    float mv0=redw[0][0][0], mv1=redw[0][0][1];
    #pragma unroll
    for (int w=1;w<8;w++){ mv0=fmaxf(mv0,redw[0][w][0]); mv1=fmaxf(mv1,redw[0][w][1]); }
    float e0=__expf(l0-mv0), e1=__expf(l1-mv1);
    *(float2*)&P[tid*2] = make_float2(e0,e1);
    float q0=wrs(e0), q1=wrs(e1);
    if (lane==0){ redw[1][wav][0]=q0; redw[1][wav][1]=q1; }
  }
  __syncthreads();
  {
    int jg = tid>>4, dq = tid&15;
    const float4* x4p = (const float4*)(xin + (size_t)b*Tn*Dn);
    float4 o0={0,0,0,0}, o1={0,0,0,0};
    int jb = jg*16;
    #pragma unroll 8
    for (int jj=0; jj<16; ++jj){
      int j = jb + jj;
      float4 xv = x4p[(size_t)j*16 + dq];
      float2 pw = *(const float2*)&P[j*2];
      o0.x=fmaf(pw.x,xv.x,o0.x); o0.y=fmaf(pw.x,xv.y,o0.y);
      o0.z=fmaf(pw.x,xv.z,o0.z); o0.w=fmaf(pw.x,xv.w,o0.w);
      o1.x=fmaf(pw.y,xv.x,o1.x); o1.y=fmaf(pw.y,xv.y,o1.y);
      o1.z=fmaf(pw.y,xv.z,o1.z); o1.w=fmaf(pw.y,xv.w,o1.w);
    }
    *(float4*)&pvp[(jg*2+0)*64 + dq*4] = o0;
    *(float4*)&pvp[(jg*2+1)*64 + dq*4] = o1;
  }
  __syncthreads();
  float o = 0.f;
  if (tid < 128){
    float ss = 0.f;
    #pragma unroll
    for (int jg=0; jg<32; ++jg) ss += pvp[(jg*2+i_)*64+d_];
    float sv = 0.f;
    #pragma unroll
    for (int w=0;w<8;w++) sv += redw[1][w][i_];
    float attn = ss/sv;
    o = xi_pre + res_scale[l]*(attn - xi_pre);
  }
  if constexpr (MODE == 0){
    if (tid < 128){
      xout[(size_t)(row0+i_)*Dn + d_] = o;
      pnorm_w(o, row0+i_, d_, sr_out);
    }
  } else if constexpr (MODE == 1){
    if (tid < 128) xout[(size_t)(row0+i_)*Dn + d_] = o;
  } else if constexpr (MODE == 2){
    if (tid < 128){
      comb[i_][d_] = o;
      comb[i_][64+d_] = prev_pre;
    }
    __syncthreads();
    gate_dot2(comb, gred, Wfb, tid, lane);
    __syncthreads();
    if (tid < 128){
      float g = sigmoidf_(gred[d_*3+i_] + bfb[d_]);
      float xg = o*g + prev_pre*(1.0f-g);
      xout[(size_t)(row0+i_)*Dn + d_] = xg;
      pnorm_w(xg, row0+i_, d_, sr_out);
    }
  } else {
    if (tid < 128){
      float c = 0.01f * rsg[0];
      xout[(size_t)(row0+i_)*Dn + d_] = o + c*(o - basin_seq[(size_t)(row0+i_)*Dn + d_]);
    }
  }
}

__global__ __launch_bounds__(256) void k_basinprep(
    const float* __restrict__ st3, const float* __restrict__ st0,
    const float* __restrict__ W_fb, const float* __restrict__ b_fb,
    float* __restrict__ xA, float* __restrict__ sA,
    const float* __restrict__ Wc1, const float* __restrict__ bc1,
    const float* __restrict__ Wc2, const float* __restrict__ bc2,
    const float* __restrict__ Wu,  const float* __restrict__ bu,
    const float* __restrict__ cb_in, float* __restrict__ cb_out,
    const float* __restrict__ W_temp, const float* __restrict__ b_temp,
    float* __restrict__ temps){
  int tid = threadIdx.x, wid = tid>>6, lane = tid&63;
  __shared__ __align__(16) float comb4[4][128];
  __shared__ float partial[256];
  __shared__ float pooled[128];
  __shared__ float h1[64];
  __shared__ float hb[128];
  __shared__ float combb[128];
  if (blockIdx.x < 256){
    int row = blockIdx.x*4 + wid;
    float xv = st3[(size_t)row*Dn+lane];
    float pvv = st0[(size_t)row*Dn+lane];
    comb4[wid][lane] = xv; comb4[wid][64+lane] = pvv;
    __syncthreads();
    const float4* W  = (const float4*)(W_fb + (size_t)lane*128);
    const float4* c4 = (const float4*)comb4[wid];
    float g0=0.f,g1=0.f;
    #pragma unroll
    for (int k=0;k<32;k+=2){
      float4 w0=W[k],   c0=c4[k];
      float4 w1=W[k+1], c1=c4[k+1];
      g0 += w0.x*c0.x + w0.y*c0.y + w0.z*c0.z + w0.w*c0.w;
      g1 += w1.x*c1.x + w1.y*c1.y + w1.z*c1.z + w1.w*c1.w;
    }
    float g = sigmoidf_(g0+g1 + b_fb[lane]);
    float xg = xv*g + pvv*(1.0f-g);
    xA[(size_t)row*Dn+lane] = xg;
    pnorm_w(xg, row, lane, sA);
  } else {
    {
      int bb = tid>>7, rem = tid&127, d = rem>>1, h = rem&1;
      const float* xb = st3 + (size_t)bb*Tn*Dn + d;
      float acc0=0.f,acc1=0.f,acc2=0.f,acc3=0.f;
      int t0 = h*256;
      for (int t=0;t<256;t+=4){
        acc0 += xb[(size_t)(t0+t  )*Dn];
        acc1 += xb[(size_t)(t0+t+1)*Dn];
        acc2 += xb[(size_t)(t0+t+2)*Dn];
        acc3 += xb[(size_t)(t0+t+3)*Dn];
      }
      partial[tid] = acc0+acc1+acc2+acc3;
    }
    __syncthreads();
    if (tid < 128){
      int bb = tid>>6, d = tid&63;
      pooled[tid] = (partial[bb*128+d*2] + partial[bb*128+d*2+1]) * (1.0f/Tn);
    }
    __syncthreads();
    if (tid < 64){
      int bb = tid >> 5, h = tid & 31;
      float acc=0.f;
      #pragma unroll 8
      for (int d2=0; d2<64; d2++) acc += pooled[bb*64+d2]*Wc1[h*64+d2];
      h1[tid] = tanhf(acc + bc1[h]);
    }
    __syncthreads();
    if (tid < 128){
      int bb = tid >> 6, d = tid & 63;
      float acc=0.f;
      #pragma unroll 8
      for (int h2=0; h2<32; h2++) acc += h1[bb*32+h2]*Wc2[d*32+h2];
      hb[tid] = tanhf(acc + bc2[d]);
    }
    __syncthreads();
    if (tid < 64){
      float agg = 0.5f*(hb[tid] + hb[64+tid]);
      combb[tid] = cb_in[tid];
      combb[64+tid] = agg;
    }
    __syncthreads();
    if (tid < 64){
      float acc=0.f;
      #pragma unroll 8
      for (int k=0;k<128;k++) acc += Wu[tid*128+k]*combb[k];
      float g = sigmoidf_(acc + bu[tid]);
      float nb = combb[tid]*(1.0f-g) + combb[64+tid]*g;
      cb_out[tid] = nb;
      #pragma unroll
      for (int l=0;l<4;l++){
        float v = wrs(W_temp[l*Dn + tid]*nb);
        if (tid==0) temps[l] = sigmoidf_(v + b_temp[l]) + 0.5f;
      }
    }
  }
}

// ======================= launcher =======================

extern "C" void kernel_launch(void* const* d_in, const int* in_sizes, int n_in,
                              void* d_out, int out_size, void* d_ws, size_t ws_size,
                              hipStream_t stream) {
  const float* basin_seq    = (const float*)d_in[0];
  const float* basin_coords = (const float*)d_in[1];
  const float* W_temp       = (const float*)d_in[2];
  const float* b_temp       = (const float*)d_in[3];
  const float* res_scale    = (const float*)d_in[4];
  const float* W_fb         = (const float*)d_in[5];
  const float* b_fb         = (const float*)d_in[6];
  const float* Wc1          = (const float*)d_in[7];
  const float* bc1          = (const float*)d_in[8];
  const float* Wc2          = (const float*)d_in[9];
  const float* bc2          = (const float*)d_in[10];
  const float* Wu           = (const float*)d_in[11];
  const float* bu           = (const float*)d_in[12];
  const float* rsg          = (const float*)d_in[13];
  float* out = (float*)d_out;
  float* ws  = (float*)d_ws;

  // one-time residency check for the cooperative path (host-side queries only)
  static int coop_ok = -1;
  if (coop_ok < 0){
    int dev = 0, coop_attr = 0, ncu = 0, nb = 0;
    hipError_t e0 = hipGetDevice(&dev);
    hipError_t e1 = hipDeviceGetAttribute(&coop_attr, hipDeviceAttributeCooperativeLaunch, dev);
    hipError_t e2 = hipDeviceGetAttribute(&ncu, hipDeviceAttributeMultiprocessorCount, dev);
    hipError_t e3 = hipOccupancyMaxActiveBlocksPerMultiprocessor(&nb, (const void*)k_fused, 512, 0);
    coop_ok = (e0==hipSuccess && e1==hipSuccess && e2==hipSuccess && e3==hipSuccess &&
               coop_attr != 0 && (long long)nb * ncu >= 256) ? 1 : 0;
  }

  if (coop_ok == 1){
    void* args[] = {
      (void*)&basin_seq, (void*)&basin_coords, (void*)&W_temp, (void*)&b_temp,
      (void*)&res_scale, (void*)&W_fb, (void*)&b_fb,
      (void*)&Wc1, (void*)&bc1, (void*)&Wc2, (void*)&bc2,
      (void*)&Wu, (void*)&bu, (void*)&rsg, (void*)&out, (void*)&ws
    };
    hipLaunchCooperativeKernel((const void*)k_fused, dim3(256), dim3(512),
                               args, 0, stream);
    return;
  }

  // fallback: known-good 10-dispatch chain (round-2)
  const size_t N = NELEM;
  float* srA   = ws;
  float* srB   = ws + N;
  float* st0   = ws + 2*N;
  float* st1   = ws + 3*N;
  float* st2   = ws + 4*N;
  float* st3   = ws + 5*N;
  float* xA    = ws + 6*N;
  float* xB    = ws + 7*N;
  float* temps = ws + 8*N;
  float* cb    = ws + 8*N + 64;

  const int GA = 512;

  k_prologue<<<257,256,0,stream>>>(basin_seq, srA, W_temp, b_temp, basin_coords, temps);
  k_attn<0><<<GA,512,0,stream>>>(basin_seq, srA, temps, res_scale, 0,
                                 st0, srB, nullptr,nullptr,nullptr,nullptr,nullptr);
  k_attn<0><<<GA,512,0,stream>>>(st0, srB, temps, res_scale, 1,
                                 st1, srA, nullptr,nullptr,nullptr,nullptr,nullptr);
  k_attn<0><<<GA,512,0,stream>>>(st1, srA, temps, res_scale, 2,
                                 st2, srB, nullptr,nullptr,nullptr,nullptr,nullptr);
  k_attn<1><<<GA,512,0,stream>>>(st2, srB, temps, res_scale, 3,
                                 st3, nullptr, nullptr,nullptr,nullptr,nullptr,nullptr);
  k_basinprep<<<257,256,0,stream>>>(st3, st0, W_fb, b_fb, xA, srA,
                                    Wc1, bc1, Wc2, bc2, Wu, bu,
                                    basin_coords, cb, W_temp, b_temp, temps);
  k_attn<2><<<GA,512,0,stream>>>(xA, srA, temps, res_scale, 0,
                                 xB, srB,
                                 W_fb + (size_t)1*Dn*2*Dn, b_fb + 1*Dn, st1, nullptr,nullptr);
  k_attn<2><<<GA,512,0,stream>>>(xB, srB, temps, res_scale, 1,
                                 xA, srA,
                                 W_fb + (size_t)2*Dn*2*Dn, b_fb + 2*Dn, st2, nullptr,nullptr);
  k_attn<2><<<GA,512,0,stream>>>(xA, srA, temps, res_scale, 2,
                                 xB, srB,
                                 W_fb + (size_t)3*Dn*2*Dn, b_fb + 3*Dn, st3, nullptr,nullptr);
  k_attn<3><<<GA,512,0,stream>>>(xB, srB, temps, res_scale, 3,
                                 out, nullptr, nullptr,nullptr,nullptr, basin_seq, rsg);
}